// Round 1
// baseline (247.208 us; speedup 1.0000x reference)
//
#include <hip/hip_runtime.h>

// shift op: out[b, g*32+c, h, w] = x[b, g*32+c, h+dh, w+dw] (zero outside),
// groups g=0..7 with offsets; channels 256..287 are zero.
// (32, 288, 64, 64) fp32. Pure memory-bound shuffle.

#define BB  32
#define CC  288
#define HH  64
#define WW  64

__global__ __launch_bounds__(1024) void shift_kernel(const float* __restrict__ x,
                                                     float* __restrict__ out) {
    const int plane = blockIdx.x;            // b*C + c   (0..9215)
    const int c     = plane % CC;
    const int g     = c >> 5;                // c / 32
    const int t     = threadIdx.x;           // 0..1023 -> one float4 of the 64x64 plane
    const int w0    = (t & 15) << 2;         // 0,4,...,60
    const int h     = t >> 4;                // 0..63

    float4* dst = (float4*)(out + (size_t)plane * (HH * WW) + h * WW + w0);

    if (g >= 8) {                            // group 8: stays zero
        *dst = make_float4(0.f, 0.f, 0.f, 0.f);
        return;
    }

    // dh/dw lookup packed as (val+1) nibbles, g0 in low nibble.
    // offsets: g0(-1,0) g1(1,0) g2(0,-1) g3(0,1) g4(-1,-1) g5(-1,1) g6(1,-1) g7(1,1)
    const int dh = (int)((0x22001120u >> (g * 4)) & 0xFu) - 1;
    const int dw = (int)((0x20202011u >> (g * 4)) & 0xFu) - 1;

    const int hs = h + dh;
    if ((unsigned)hs >= (unsigned)HH) {      // whole row out of bounds -> zero
        *dst = make_float4(0.f, 0.f, 0.f, 0.f);
        return;
    }

    const float* __restrict__ row = x + (size_t)plane * (HH * WW) + hs * WW;

    float4 v;
    if (dw == 0) {
        // aligned vector load
        v = *(const float4*)(row + w0);
    } else {
        // misaligned by one element: scalar dword loads, edge-predicated.
        // consecutive lanes still hit consecutive addresses (coalesced).
        const int ws = w0 + dw;
        v.x = ((unsigned)(ws    ) < (unsigned)WW) ? row[ws    ] : 0.f;
        v.y = ((unsigned)(ws + 1) < (unsigned)WW) ? row[ws + 1] : 0.f;
        v.z = ((unsigned)(ws + 2) < (unsigned)WW) ? row[ws + 2] : 0.f;
        v.w = ((unsigned)(ws + 3) < (unsigned)WW) ? row[ws + 3] : 0.f;
    }
    *dst = v;
}

extern "C" void kernel_launch(void* const* d_in, const int* in_sizes, int n_in,
                              void* d_out, int out_size, void* d_ws, size_t ws_size,
                              hipStream_t stream) {
    const float* x = (const float*)d_in[0];
    float* out = (float*)d_out;
    // one block per (b,c) plane; 1024 threads x float4 = 4096 floats = 64x64
    shift_kernel<<<dim3(BB * CC), dim3(1024), 0, stream>>>(x, out);
}

// Round 2
// 242.746 us; speedup vs baseline: 1.0184x; 1.0184x over previous
//
#include <hip/hip_runtime.h>

// shift op: out[b, g*32+c, h, w] = x[b, g*32+c, h+dh, w+dw] (zero outside),
// groups g=0..7 with offsets; channels 256..287 stay zero.
// (32, 288, 64, 64) fp32. Pure memory-bound shuffle: 285 MB total -> ~50us floor.
//
// Layout: 256-thread blocks, 4 blocks per (b,c) plane (16 rows each).
// Every thread: ONE aligned dwordx4 load + ONE aligned dwordx4 store.
// The w+-1 shift is reconstructed via a single cross-lane __shfl (lane+1 holds
// the next float4 of the same row), instead of 4 strided scalar loads.

#define CC  288
#define HH  64
#define WW  64

__global__ __launch_bounds__(256) void shift_kernel(const float* __restrict__ x,
                                                    float* __restrict__ out) {
    const int blk     = blockIdx.x;
    const int plane   = blk >> 2;            // b*C + c   (0..9215)
    const int quarter = blk & 3;             // 16-row slab
    const int c       = plane % CC;
    const int g       = c >> 5;              // c / 32

    const int t  = threadIdx.x;              // 0..255
    const int w0 = (t & 15) << 2;            // 0,4,...,60
    const int h  = (quarter << 4) + (t >> 4);

    float4* dst = (float4*)(out + (size_t)plane * (HH * WW) + h * WW + w0);

    if (g >= 8) {                            // group 8: stays zero
        *dst = make_float4(0.f, 0.f, 0.f, 0.f);
        return;
    }

    // offsets: g0(-1,0) g1(1,0) g2(0,-1) g3(0,1) g4(-1,-1) g5(-1,1) g6(1,-1) g7(1,1)
    const int dh = (int)((0x22001120u >> (g * 4)) & 0xFu) - 1;
    const int dw = (int)((0x20202011u >> (g * 4)) & 0xFu) - 1;

    const int hs = h + dh;
    if ((unsigned)hs >= (unsigned)HH) {      // whole row out of bounds -> zero
        *dst = make_float4(0.f, 0.f, 0.f, 0.f);
        return;
    }

    const float* __restrict__ row = x + (size_t)plane * (HH * WW) + hs * WW;

    // single aligned 16B load of the source row segment this thread owns
    float4 a = *(const float4*)(row + w0);

    float4 v;
    const int lane = t & 63;
    if (dw == 0) {
        v = a;
    } else if (dw == 1) {
        // out[w] = row[w+1]; row[w0+4] == lane+1's a.x (same row: lanes 0..15)
        float nx = __shfl(a.x, lane + 1);
        v.x = a.y; v.y = a.z; v.z = a.w;
        v.w = (w0 == 60) ? 0.f : nx;         // row boundary -> zero (also masks wave edge)
    } else {
        // out[w] = row[w-1]; row[w0-1] == lane-1's a.w
        float pw = __shfl(a.w, lane - 1);
        v.x = (w0 == 0) ? 0.f : pw;
        v.y = a.x; v.z = a.y; v.w = a.z;
    }
    *dst = v;
}

extern "C" void kernel_launch(void* const* d_in, const int* in_sizes, int n_in,
                              void* d_out, int out_size, void* d_ws, size_t ws_size,
                              hipStream_t stream) {
    const float* x = (const float*)d_in[0];
    float* out = (float*)d_out;
    // 4 blocks per (b,c) plane; 256 threads x float4 = 1024 floats = 16 rows
    shift_kernel<<<dim3(32 * CC * 4), dim3(256), 0, stream>>>(x, out);
}